// Round 3
// baseline (306.957 us; speedup 1.0000x reference)
//
#include <hip/hip_runtime.h>

namespace {
constexpr int Bn = 8, Cn = 256, Hn = 64, Wn = 64;
constexpr int Kk = 5, PAD = 2, KMC = 100;   // KMC = UP^2 * K^2
constexpr int SPLIT  = 4;                   // channel-range splits across grid
constexpr int GROUPS = Cn / 16 / SPLIT;     // 4 channel-group iters per block

typedef float f32x2 __attribute__((ext_vector_type(2)));  // native vec for
                                                          // nontemporal store
}

// grid (H, B, SPLIT), block 256 = 4 waves; lane = w; wave wv handles 4
// channels per group iteration. LDS tiles are WAVE-PRIVATE -> no
// __syncthreads; per-wave lgkmcnt fences only (waves run decoupled).
__global__ __launch_bounds__(256, 4) void carafe_fwd(
    const float* __restrict__ x,    // [B, C, H, W]
    const float* __restrict__ km,   // [B, 100, H, W]
    float* __restrict__ out)        // [B, C, 2H, 2W]
{
    const int h   = blockIdx.x;
    const int b   = blockIdx.y;
    const int cs  = blockIdx.z;     // which 64-channel slab
    const int tid = threadIdx.x;
    const int wv  = tid >> 6;
    const int w   = tid & 63;

    // wave-private staging tile, channel-interleaved for aligned b128 taps
    __shared__ __align__(16) float xs[4][Kk][68][4];

    // zero horizontal halo columns (padded cols 0,1,66,67) once per wave
    if (w < Kk * 4) {
        const int r  = w >> 2;
        const int hc = w & 3;
        const int wp = (hc < 2) ? hc : 64 + hc;
        #pragma unroll
        for (int k = 0; k < 4; ++k) xs[wv][r][wp][k] = 0.0f;
    }

    // per-pixel reassembly weights -> 100 registers (reused over 64 channels)
    float wreg[KMC];
    {
        const float* kmp = km + (((size_t)b * KMC) * Hn + h) * Wn + w;
        #pragma unroll
        for (int ch = 0; ch < KMC; ++ch)
            wreg[ch] = kmp[(size_t)ch * (Hn * Wn)];
    }

    const float* xb = x + (size_t)b * Cn * Hn * Wn;
    float* ob       = out + (size_t)b * Cn * (2 * Hn) * (2 * Wn);

    for (int g = 0; g < GROUPS; ++g) {
        const int c0 = cs * (Cn / SPLIT) + g * 16 + wv * 4;

        // stage 4 channels x 5 rows (rows h-2..h+2, zero-padded) into LDS
        #pragma unroll
        for (int r = 0; r < Kk; ++r) {
            const int hr = h - PAD + r;
            float4 v;
            if (hr >= 0 && hr < Hn) {
                const float* xr = xb + ((size_t)c0 * Hn + hr) * Wn + w;
                v.x = xr[0 * Hn * Wn];
                v.y = xr[1 * Hn * Wn];
                v.z = xr[2 * Hn * Wn];
                v.w = xr[3 * Hn * Wn];
            } else {
                v = make_float4(0.f, 0.f, 0.f, 0.f);
            }
            *(float4*)(&xs[wv][r][w + PAD][0]) = v;
        }

        // wave-level fence: all my wave's ds_writes visible before ds_reads
        // (cross-lane RAW within the wave; no inter-wave dependency exists)
        asm volatile("s_waitcnt lgkmcnt(0)" ::: "memory");

        float acc[4][4] = {};  // [channel k][subpixel u]
        #pragma unroll
        for (int kh = 0; kh < Kk; ++kh) {
            #pragma unroll
            for (int kw = 0; kw < Kk; ++kw) {
                const float4 tap = *(const float4*)(&xs[wv][kh][w + kw][0]);
                const int t = kh * Kk + kw;
                #pragma unroll
                for (int u = 0; u < 4; ++u) {
                    const float wt = wreg[u * 25 + t];
                    acc[0][u] += tap.x * wt;
                    acc[1][u] += tap.y * wt;
                    acc[2][u] += tap.z * wt;
                    acc[3][u] += tap.w * wt;
                }
            }
        }

        // WAR fence: reads drained before next iteration overwrites the tile
        asm volatile("s_waitcnt lgkmcnt(0)" ::: "memory");

        // out[b, c0+k, 2h+i, 2w+j]; nontemporal (write-once stream) so the
        // 131 MB of stores don't evict x/km from L2/L3
        #pragma unroll
        for (int k = 0; k < 4; ++k) {
            #pragma unroll
            for (int i = 0; i < 2; ++i) {
                f32x2 o2 = {acc[k][2 * i + 0], acc[k][2 * i + 1]};
                f32x2* p = (f32x2*)(&ob[((size_t)(c0 + k) * (2 * Hn) +
                                         (2 * h + i)) * (2 * Wn) + 2 * w]);
                __builtin_nontemporal_store(o2, p);
            }
        }
    }
}

extern "C" void kernel_launch(void* const* d_in, const int* in_sizes, int n_in,
                              void* d_out, int out_size, void* d_ws, size_t ws_size,
                              hipStream_t stream)
{
    const float* x  = (const float*)d_in[0];
    const float* km = (const float*)d_in[1];
    float* out      = (float*)d_out;

    dim3 grid(Hn, Bn, SPLIT);
    carafe_fwd<<<grid, 256, 0, stream>>>(x, km, out);
}

// Round 4
// 212.529 us; speedup vs baseline: 1.4443x; 1.4443x over previous
//
#include <hip/hip_runtime.h>

namespace {
constexpr int Bn = 8, Cn = 256, Hn = 64, Wn = 64;
constexpr int Kk = 5, PAD = 2, KMC = 100;   // KMC = UP^2 * K^2
constexpr int SPLIT  = 4;                   // channel-range splits across grid
constexpr int GROUPS = Cn / 16 / SPLIT;     // 4 channel-group iters per block

typedef float f32x2 __attribute__((ext_vector_type(2)));
}

// grid (H, B, SPLIT), block 256 = 4 waves; lane = w; wave wv handles 4
// channels per group iteration. LDS tiles are WAVE-PRIVATE -> no
// __syncthreads; per-wave lgkmcnt fences only (waves run decoupled).
// NOTE R3 lesson: NO nontemporal stores — 8B/lane NT stores bypass L2
// write-combining and amplified WRITE_SIZE 2.3x (131->294 MB).
__global__ __launch_bounds__(256, 4) void carafe_fwd(
    const float* __restrict__ x,    // [B, C, H, W]
    const float* __restrict__ km,   // [B, 100, H, W]
    float* __restrict__ out)        // [B, C, 2H, 2W]
{
    const int h   = blockIdx.x;
    const int b   = blockIdx.y;
    const int cs  = blockIdx.z;     // which 64-channel slab
    const int tid = threadIdx.x;
    const int wv  = tid >> 6;
    const int w   = tid & 63;

    // wave-private staging tile, channel-interleaved for aligned b128 taps
    __shared__ __align__(16) float xs[4][Kk][68][4];

    // zero horizontal halo columns (padded cols 0,1,66,67) once per wave
    if (w < Kk * 4) {
        const int r  = w >> 2;
        const int hc = w & 3;
        const int wp = (hc < 2) ? hc : 64 + hc;
        #pragma unroll
        for (int k = 0; k < 4; ++k) xs[wv][r][wp][k] = 0.0f;
    }

    // per-pixel reassembly weights, packed as u-pairs so the u-dimension
    // FMAs become v_pk_fma_f32: wpk[t][p] = {wt(2p,t), wt(2p+1,t)}
    f32x2 wpk[25][2];
    {
        const float* kmp = km + (((size_t)b * KMC) * Hn + h) * Wn + w;
        #pragma unroll
        for (int t = 0; t < 25; ++t) {
            #pragma unroll
            for (int p = 0; p < 2; ++p) {
                wpk[t][p].x = kmp[(size_t)((2 * p + 0) * 25 + t) * (Hn * Wn)];
                wpk[t][p].y = kmp[(size_t)((2 * p + 1) * 25 + t) * (Hn * Wn)];
            }
        }
    }

    const float* xb = x + (size_t)b * Cn * Hn * Wn;
    float* ob       = out + (size_t)b * Cn * (2 * Hn) * (2 * Wn);

    for (int g = 0; g < GROUPS; ++g) {
        const int c0 = cs * (Cn / SPLIT) + g * 16 + wv * 4;

        // stage 4 channels x 5 rows (rows h-2..h+2, zero-padded) into LDS
        #pragma unroll
        for (int r = 0; r < Kk; ++r) {
            const int hr = h - PAD + r;
            float4 v;
            if (hr >= 0 && hr < Hn) {
                const float* xr = xb + ((size_t)c0 * Hn + hr) * Wn + w;
                v.x = xr[0 * Hn * Wn];
                v.y = xr[1 * Hn * Wn];
                v.z = xr[2 * Hn * Wn];
                v.w = xr[3 * Hn * Wn];
            } else {
                v = make_float4(0.f, 0.f, 0.f, 0.f);
            }
            *(float4*)(&xs[wv][r][w + PAD][0]) = v;
        }

        // wave-level fence: my wave's ds_writes visible before ds_reads
        // (cross-lane RAW within the wave; no inter-wave dependency exists)
        asm volatile("s_waitcnt lgkmcnt(0)" ::: "memory");

        f32x2 acc[4][2] = {};  // [channel k][u-pair p] — packed fp32 FMA
        #pragma unroll
        for (int kh = 0; kh < Kk; ++kh) {
            #pragma unroll
            for (int kw = 0; kw < Kk; ++kw) {
                const float4 tap = *(const float4*)(&xs[wv][kh][w + kw][0]);
                const int t = kh * Kk + kw;
                #pragma unroll
                for (int p = 0; p < 2; ++p) {
                    const f32x2 wt = wpk[t][p];
                    acc[0][p] += tap.x * wt;
                    acc[1][p] += tap.y * wt;
                    acc[2][p] += tap.z * wt;
                    acc[3][p] += tap.w * wt;
                }
            }
        }

        // WAR fence: reads drained before next iteration overwrites the tile
        asm volatile("s_waitcnt lgkmcnt(0)" ::: "memory");

        // out[b, c0+k, 2h+i, 2w+j]; u = i*2+j -> pair p=i holds (j=0, j=1);
        // lane-consecutive float2 -> 512B contiguous per wave store
        #pragma unroll
        for (int k = 0; k < 4; ++k) {
            #pragma unroll
            for (int i = 0; i < 2; ++i) {
                f32x2* p = (f32x2*)(&ob[((size_t)(c0 + k) * (2 * Hn) +
                                         (2 * h + i)) * (2 * Wn) + 2 * w]);
                *p = acc[k][i];
            }
        }
    }
}

extern "C" void kernel_launch(void* const* d_in, const int* in_sizes, int n_in,
                              void* d_out, int out_size, void* d_ws, size_t ws_size,
                              hipStream_t stream)
{
    const float* x  = (const float*)d_in[0];
    const float* km = (const float*)d_in[1];
    float* out      = (float*)d_out;

    dim3 grid(Hn, Bn, SPLIT);
    carafe_fwd<<<grid, 256, 0, stream>>>(x, km, out);
}